// Round 10
// baseline (479.919 us; speedup 1.0000x reference)
//
#include <hip/hip_runtime.h>
#include <hip/hip_cooperative_groups.h>
#include <stdint.h>

namespace cg = cooperative_groups;

#define B_ 16
#define N_ 25200
#define NC_ 80
#define TOPK 2048
#define MAXDET 300
#define CONF_T 0.25f
#define IOU_T 0.45f
#define MAX_WH_ 4096.0f
#define NBINS 4096
#define CAP 6144       // superset bound after level-1 threshold (~2.6k realistic)
#define CLS_CAP 256
#define CNT_STRIDE 32
#define GRID_ 512      // 2 blocks/CU on 256 CUs -> cooperative co-residency safe
#define TILES_ 1575    // B_*N_/256
#define CTILES_ 99     // ceil(N_/256)
#define RCH_ 24        // CAP/256 rank chunks per batch

// ---------------- workspace layout (host+device agree) ----------------
// [0)        hist1      B*NBINS*4      = 262144
// [262144)   keepmask   B*64*4         = 4096
// [266240)   cnt        B*32*4         = 2048
// [268288)   topk_score B*TOPK*4       = 131072   (zero region ends: 399360)
// [399360)   b1v        64
// [399424)   keys       B*N*4          = 1612800
// [2012224)  cls        B*N*4          = 1612800
// [3625024)  cand       B*CAP*8        = 786432
// [4411456)  box4       B*TOPK*16     = 524288
// [4935744)  clsf       B*TOPK*4      = 131072
#define OFF_HIST1   0
#define OFF_KEEP    262144
#define OFF_CNT     266240
#define OFF_TSC     268288
#define ZERO_BYTES  399360
#define OFF_B1V     399360
#define OFF_KEYS    399424
#define OFF_CLS     2012224
#define OFF_CAND    3625024
#define OFF_BOX4    4411456
#define OFF_CLSF    4935744

// ================= fused cooperative kernel =================
__global__ __launch_bounds__(256, 2) void k_all(const float* __restrict__ pred,
                                                char* __restrict__ ws,
                                                float* __restrict__ out) {
  uint32_t* hist1 = (uint32_t*)(ws + OFF_HIST1);
  uint32_t* keepmask = (uint32_t*)(ws + OFF_KEEP);
  uint32_t* cnt = (uint32_t*)(ws + OFF_CNT);
  float* topk_score = (float*)(ws + OFF_TSC);
  uint32_t* b1v = (uint32_t*)(ws + OFF_B1V);
  uint32_t* keys = (uint32_t*)(ws + OFF_KEYS);
  uint32_t* cls = (uint32_t*)(ws + OFF_CLS);
  unsigned long long* cand = (unsigned long long*)(ws + OFF_CAND);
  float4* box4 = (float4*)(ws + OFF_BOX4);
  float* clsf = (float*)(ws + OFF_CLSF);
  float* out_counts = out + (size_t)B_ * MAXDET * 6;

  __shared__ __align__(16) unsigned char smem[CAP * 8];  // 48KB phase union
  __shared__ uint32_t s_cnt, s_base;

  const int tid = threadIdx.x;
  cg::grid_group grid = cg::this_grid();

  // ---- Phase A: zero hist1+keepmask+cnt+topk_score ----
  {
    uint4* zp = (uint4*)ws;
    for (int i = blockIdx.x * 256 + tid; i < ZERO_BYTES / 16; i += GRID_ * 256)
      zp[i] = make_uint4(0u, 0u, 0u, 0u);
  }
  grid.sync();

  // ---- Phase B: score/class + level-1 histogram (grid-stride tiles) ----
  {
    float* sh = (float*)smem;                       // 64*85 floats = 21760B
    uint32_t* lh = (uint32_t*)(smem + 21760);       // 16KB
    const int a = tid >> 2, ch = tid & 3;
    for (int tile = blockIdx.x; tile < TILES_; tile += GRID_) {
      const int base_gid = tile * 256;
      const int blk_b = base_gid / N_;
      const bool one_batch = (blk_b == (base_gid + 255) / N_);
      if (one_batch)
        for (int i = tid; i < NBINS; i += 256) lh[i] = 0;
      for (int chunk = 0; chunk < 4; ++chunk) {
        const float4* src =
            (const float4*)(pred + ((size_t)base_gid + chunk * 64) * 85);
        __syncthreads();  // prev compute done + lh zero visible
        for (int i = tid; i < 64 * 85 / 4; i += 256) ((float4*)sh)[i] = src[i];
        __syncthreads();
        const int gid = base_gid + chunk * 64 + a;
        const float* row = sh + a * 85;
        const float obj = row[4];
        float best = -1.0f;
        int bj = 0;
#pragma unroll
        for (int i = 0; i < 20; ++i) {
          float v = row[5 + ch * 20 + i] * obj;  // plain mul, matches ref
          if (v > best) { best = v; bj = ch * 20 + i; }  // strict >: first max
        }
#pragma unroll
        for (int d = 1; d < 4; d <<= 1) {
          float vo = __shfl_xor(best, d, 64);
          int jo = __shfl_xor(bj, d, 64);
          if (vo > best || (vo == best && jo < bj)) { best = vo; bj = jo; }
        }
        if (ch == 0) {
          bool valid = (obj > CONF_T) && (best > CONF_T);
          float score = valid ? best : 0.0f;
          uint32_t key = __float_as_uint(score);  // score>=0: order-isomorphic
          keys[gid] = key;
          cls[gid] = (uint32_t)bj;
          if (score > CONF_T) {
            if (one_batch) atomicAdd(&lh[key >> 19], 1u);
            else atomicAdd(&hist1[(size_t)(gid / N_) * NBINS + (key >> 19)], 1u);
          }
        }
      }
      if (one_batch) {
        __syncthreads();
        for (int i = tid; i < NBINS; i += 256) {
          uint32_t cn = lh[i];
          if (cn) atomicAdd(&hist1[(size_t)blk_b * NBINS + i], cn);
        }
      }
    }
  }
  grid.sync();

  // ---- Phase C: level-1 threshold (blocks 0..15) ----
  if (blockIdx.x < B_) {
    uint32_t* sums = (uint32_t*)smem;
    const int b = blockIdx.x;
    const uint32_t* h = hist1 + (size_t)b * NBINS + tid * 16;
    uint32_t v[16];
    uint32_t loc = 0;
#pragma unroll
    for (int i = 0; i < 16; ++i) { v[i] = h[i]; loc += v[i]; }
    sums[tid] = loc;
    for (int d = 1; d < 256; d <<= 1) {
      __syncthreads();
      uint32_t y = (tid + d < 256) ? sums[tid + d] : 0;
      __syncthreads();
      sums[tid] += y;
    }
    __syncthreads();
    const uint32_t need = TOPK;
    uint32_t above = (tid + 1 < 256) ? sums[tid + 1] : 0;
    if (above < need && sums[tid] >= need) {
      uint32_t cum = above;
      for (int i = 15; i >= 0; --i) {
        if (cum + v[i] >= need) { b1v[b] = (uint32_t)(tid * 16 + i); break; }
        cum += v[i];
      }
    }
    if (tid == 0 && sums[0] < need) b1v[b] = 1;  // <2048 valid: take all valid
  }
  grid.sync();

  // ---- Phase D: compact candidates (grid-stride virtual tiles) ----
  for (int vt = blockIdx.x; vt < CTILES_ * B_; vt += GRID_) {
    int b = vt / CTILES_;
    int t = vt - b * CTILES_;
    int n = t * 256 + tid;
    __syncthreads();  // prev iter's s_cnt reads done
    if (tid == 0) s_cnt = 0;
    __syncthreads();
    uint32_t k = 0, loc = 0xFFFFFFFFu;
    if (n < N_) {
      k = keys[(size_t)b * N_ + n];
      if ((k >> 19) >= b1v[b]) loc = atomicAdd(&s_cnt, 1u);
    }
    __syncthreads();
    if (tid == 0) s_base = atomicAdd(&cnt[b * CNT_STRIDE], s_cnt);
    __syncthreads();
    if (loc != 0xFFFFFFFFu) {
      uint32_t p = s_base + loc;
      if (p < CAP)
        cand[(size_t)b * CAP + p] =
            ((unsigned long long)k << 32) | (uint32_t)(~(uint32_t)n);
    }
  }
  grid.sync();

  // ---- Phase E: exact rank by counting + gather ----
  {
    unsigned long long* csh = (unsigned long long*)smem;
    for (int vj = blockIdx.x; vj < RCH_ * B_; vj += GRID_) {
      int b = vj / RCH_;
      int chunk = vj - b * RCH_;
      int n = (int)cnt[b * CNT_STRIDE];
      if (n > CAP) n = CAP;
      if (chunk * 256 >= n) continue;  // block-uniform
      const unsigned long long* cb = cand + (size_t)b * CAP;
      __syncthreads();  // prev job's reads done before overwrite
      for (int i = tid; i < n; i += 256) csh[i] = cb[i];
      __syncthreads();
      int own = chunk * 256 + tid;
      if (own < n) {
        const unsigned long long ki = csh[own];
        uint32_t rank = 0;
        int j = 0;
        for (; j + 8 <= n; j += 8) {
#pragma unroll
          for (int u = 0; u < 8; ++u) rank += (csh[j + u] > ki) ? 1u : 0u;
        }
        for (; j < n; ++j) rank += (csh[j] > ki) ? 1u : 0u;
        if (rank < TOPK) {
          uint32_t idx = ~((uint32_t)(ki & 0xFFFFFFFFull));
          topk_score[(size_t)b * TOPK + rank] =
              __uint_as_float((uint32_t)(ki >> 32));
          const float* p = pred + ((size_t)b * N_ + idx) * 85;
          float x = p[0], y = p[1], w = p[2], h = p[3];
          float hw = w * 0.5f, hh = h * 0.5f;  // exact (pow2 scale)
          box4[(size_t)b * TOPK + rank] =
              make_float4(x - hw, y - hh, x + hw, y + hh);
          clsf[(size_t)b * TOPK + rank] = (float)cls[(size_t)b * N_ + idx];
        }
      }
    }
  }
  grid.sync();

  // ---- Phase F: per-class greedy NMS (grid-stride pairs; 4 waves duplicate
  //      the same pair -> __syncthreads legal, LDS writes same-value, atomicOr
  //      idempotent). Cross-class IoU is exactly 0 (offset 4096 >> extent). ----
  {
    float4* ob = (float4*)smem;                  // 4KB
    uint32_t* rk = (uint32_t*)(smem + 4096);     // 1KB
    const int l = tid & 63;
    for (int pj = blockIdx.x; pj < NC_ * B_; pj += GRID_) {
      int b = pj / NC_;
      int c = pj - b * NC_;
      const float cf = (float)c;
      const float offv = cf * MAX_WH_;  // exact (pow2 scale)
      __syncthreads();  // prev pair's reads done before overwrite
      int n = 0;
      for (int chunk = 0; chunk < TOPK / 64; ++chunk) {
        int r = chunk * 64 + l;
        float s = topk_score[(size_t)b * TOPK + r];
        float cv = clsf[(size_t)b * TOPK + r];
        bool m = (s > CONF_T) && (cv == cf);
        unsigned long long mask = __ballot(m);
        if (m) {
          int pos = n + __popcll(mask & ((1ull << l) - 1ull));
          if (pos < CLS_CAP) {
            float4 bx = box4[(size_t)b * TOPK + r];
            ob[pos] = make_float4(__fadd_rn(bx.x, offv), __fadd_rn(bx.y, offv),
                                  __fadd_rn(bx.z, offv), __fadd_rn(bx.w, offv));
            rk[pos] = (uint32_t)r;
          }
        }
        n += (int)__popcll(mask);
      }
      if (n > CLS_CAP) n = CLS_CAP;
      __syncthreads();
      float4 bj[4]; float aj[4];
#pragma unroll
      for (int t = 0; t < 4; ++t) {
        int j = l + 64 * t;
        if (j < n) {
          bj[t] = ob[j];
          aj[t] = __fmul_rn(__fsub_rn(bj[t].z, bj[t].x),
                            __fsub_rn(bj[t].w, bj[t].y));
        }
      }
      uint32_t supp = 0, keptbits = 0;
      for (int i = 0; i < n; ++i) {
        int owner = i & 63, word = i >> 6;
        uint32_t so = (uint32_t)__shfl((int)supp, owner, 64);
        bool kept_i = !((so >> word) & 1u);
        if (l == owner && kept_i) keptbits |= 1u << word;
        if (kept_i) {
          float4 bi = ob[i];
          float a1 = __fmul_rn(__fsub_rn(bi.z, bi.x), __fsub_rn(bi.w, bi.y));
#pragma unroll
          for (int t = 0; t < 4; ++t) {
            int j = l + 64 * t;
            if (j > i && j < n && !((supp >> t) & 1u)) {
              float ltx = fmaxf(bi.x, bj[t].x), lty = fmaxf(bi.y, bj[t].y);
              float rbx = fminf(bi.z, bj[t].z), rby = fminf(bi.w, bj[t].w);
              float dx = fmaxf(__fsub_rn(rbx, ltx), 0.0f);
              float dy = fmaxf(__fsub_rn(rby, lty), 0.0f);
              float inter = __fmul_rn(dx, dy);
              float uni = __fsub_rn(__fadd_rn(a1, aj[t]), inter);
              if (inter > 0.0f && __fdiv_rn(inter, uni) > IOU_T) supp |= 1u << t;
            }
          }
        }
      }
#pragma unroll
      for (int t = 0; t < 4; ++t) {
        int j = l + 64 * t;
        if (j < n && ((keptbits >> t) & 1u)) {
          uint32_t r = rk[j];
          atomicOr(&keepmask[b * 64 + (r >> 5)], 1u << (r & 31));
        }
      }
    }
  }
  grid.sync();

  // ---- Phase G: emit up to 300 rows + count (blocks 0..15) ----
  if (blockIdx.x < B_) {
    const int b = blockIdx.x;
    float* ob_ = out + (size_t)b * MAXDET * 6;
    for (int t = tid; t < MAXDET * 6; t += 256) ob_[t] = 0.0f;
    __syncthreads();
    if (tid < 64) {
      const int l = tid;
      uint32_t w = keepmask[b * 64 + l];
      int pc = __popc(w);
      int pre = pc;
      for (int off = 1; off < 64; off <<= 1) {
        int v = __shfl_up(pre, off, 64);
        if (l >= off) pre += v;
      }
      if (l == 63) out_counts[b] = (float)pre;
      int r = pre - pc;
      for (int jj = 0; jj < 32; ++jj) {
        if ((w >> jj) & 1u) {
          if (r < MAXDET) {
            int k = l * 32 + jj;
            float4 bx = box4[(size_t)b * TOPK + k];
            float sc = topk_score[(size_t)b * TOPK + k];
            float cf = clsf[(size_t)b * TOPK + k];
            float* row = ob_ + (size_t)r * 6;
            row[0] = bx.x; row[1] = bx.y; row[2] = bx.z; row[3] = bx.w;
            row[4] = sc;   row[5] = cf;
          }
          ++r;
        }
      }
    }
  }
}

// ================= fallback path (round-9 pipeline) =================
__global__ __launch_bounds__(256) void k_zero(uint4* __restrict__ p, int n16) {
  int i = blockIdx.x * 256 + threadIdx.x;
  if (i < n16) p[i] = make_uint4(0u, 0u, 0u, 0u);
}

__global__ __launch_bounds__(256) void k_score(const float* __restrict__ pred,
                                               uint32_t* __restrict__ keys,
                                               uint32_t* __restrict__ cls,
                                               uint32_t* __restrict__ hist1) {
  __shared__ float sh[64 * 85];
  __shared__ uint32_t lh[NBINS];
  const int tid = threadIdx.x;
  const int a = tid >> 2, ch = tid & 3;
  const int base_gid = blockIdx.x * 256;
  const int blk_b = base_gid / N_;
  const bool one_batch = (blk_b == (base_gid + 255) / N_);
  if (one_batch)
    for (int i = tid; i < NBINS; i += 256) lh[i] = 0;
  for (int chunk = 0; chunk < 4; ++chunk) {
    const float4* src =
        (const float4*)(pred + ((size_t)base_gid + chunk * 64) * 85);
    __syncthreads();
    for (int i = tid; i < 64 * 85 / 4; i += 256) ((float4*)sh)[i] = src[i];
    __syncthreads();
    const int gid = base_gid + chunk * 64 + a;
    const float* row = sh + a * 85;
    const float obj = row[4];
    float best = -1.0f;
    int bj = 0;
#pragma unroll
    for (int i = 0; i < 20; ++i) {
      float v = row[5 + ch * 20 + i] * obj;
      if (v > best) { best = v; bj = ch * 20 + i; }
    }
#pragma unroll
    for (int d = 1; d < 4; d <<= 1) {
      float vo = __shfl_xor(best, d, 64);
      int jo = __shfl_xor(bj, d, 64);
      if (vo > best || (vo == best && jo < bj)) { best = vo; bj = jo; }
    }
    if (ch == 0) {
      bool valid = (obj > CONF_T) && (best > CONF_T);
      float score = valid ? best : 0.0f;
      uint32_t key = __float_as_uint(score);
      keys[gid] = key;
      cls[gid] = (uint32_t)bj;
      if (score > CONF_T) {
        if (one_batch) atomicAdd(&lh[key >> 19], 1u);
        else atomicAdd(&hist1[(size_t)(gid / N_) * NBINS + (key >> 19)], 1u);
      }
    }
  }
  if (one_batch) {
    __syncthreads();
    for (int i = tid; i < NBINS; i += 256) {
      uint32_t cn = lh[i];
      if (cn) atomicAdd(&hist1[(size_t)blk_b * NBINS + i], cn);
    }
  }
}

__global__ __launch_bounds__(256) void k_thresh(const uint32_t* __restrict__ hist,
                                                uint32_t* __restrict__ b_out) {
  __shared__ uint32_t sums[256];
  const int b = blockIdx.x;
  const int t = threadIdx.x;
  const uint32_t* h = hist + (size_t)b * NBINS + t * 16;
  uint32_t v[16];
  uint32_t loc = 0;
#pragma unroll
  for (int i = 0; i < 16; ++i) { v[i] = h[i]; loc += v[i]; }
  sums[t] = loc;
  for (int d = 1; d < 256; d <<= 1) {
    __syncthreads();
    uint32_t y = (t + d < 256) ? sums[t + d] : 0;
    __syncthreads();
    sums[t] += y;
  }
  __syncthreads();
  const uint32_t need = TOPK;
  uint32_t above = (t + 1 < 256) ? sums[t + 1] : 0;
  if (above < need && sums[t] >= need) {
    uint32_t cum = above;
    for (int i = 15; i >= 0; --i) {
      if (cum + v[i] >= need) { b_out[b] = (uint32_t)(t * 16 + i); break; }
      cum += v[i];
    }
  }
  if (t == 0 && sums[0] < need) b_out[b] = 1;
}

__global__ __launch_bounds__(256) void k_compact(const uint32_t* __restrict__ keys,
                                                 const uint32_t* __restrict__ b1v,
                                                 uint32_t* __restrict__ cnt,
                                                 unsigned long long* __restrict__ cand) {
  __shared__ uint32_t s_cnt, s_base;
  const int b = blockIdx.y;
  const int n = blockIdx.x * 256 + threadIdx.x;
  if (threadIdx.x == 0) s_cnt = 0;
  __syncthreads();
  uint32_t k = 0, loc = 0xFFFFFFFFu;
  if (n < N_) {
    k = keys[(size_t)b * N_ + n];
    if ((k >> 19) >= b1v[b]) loc = atomicAdd(&s_cnt, 1u);
  }
  __syncthreads();
  if (threadIdx.x == 0) s_base = atomicAdd(&cnt[b * CNT_STRIDE], s_cnt);
  __syncthreads();
  if (loc != 0xFFFFFFFFu) {
    uint32_t p = s_base + loc;
    if (p < CAP)
      cand[(size_t)b * CAP + p] = ((unsigned long long)k << 32) | (uint32_t)(~(uint32_t)n);
  }
}

__global__ __launch_bounds__(128) void k_rank(const float* __restrict__ pred,
                                              const uint32_t* __restrict__ cls,
                                              const unsigned long long* __restrict__ cand,
                                              const uint32_t* __restrict__ cnt,
                                              float* __restrict__ topk_score,
                                              float4* __restrict__ box4,
                                              float* __restrict__ clsf) {
  __shared__ unsigned long long sh[CAP];
  const int b = blockIdx.y;
  int n = (int)cnt[b * CNT_STRIDE];
  if (n > CAP) n = CAP;
  const int own = blockIdx.x * 128 + threadIdx.x;
  if (blockIdx.x * 128 >= n) return;
  const unsigned long long* cb = cand + (size_t)b * CAP;
  for (int i = threadIdx.x; i < n; i += 128) sh[i] = cb[i];
  __syncthreads();
  if (own >= n) return;
  const unsigned long long ki = sh[own];
  uint32_t rank = 0;
  int j = 0;
  for (; j + 8 <= n; j += 8) {
#pragma unroll
    for (int u = 0; u < 8; ++u) rank += (sh[j + u] > ki) ? 1u : 0u;
  }
  for (; j < n; ++j) rank += (sh[j] > ki) ? 1u : 0u;
  if (rank < TOPK) {
    uint32_t idx = ~((uint32_t)(ki & 0xFFFFFFFFull));
    topk_score[(size_t)b * TOPK + rank] = __uint_as_float((uint32_t)(ki >> 32));
    const float* p = pred + ((size_t)b * N_ + idx) * 85;
    float x = p[0], y = p[1], w = p[2], h = p[3];
    float hw = w * 0.5f, hh = h * 0.5f;
    box4[(size_t)b * TOPK + rank] = make_float4(x - hw, y - hh, x + hw, y + hh);
    clsf[(size_t)b * TOPK + rank] = (float)cls[(size_t)b * N_ + idx];
  }
}

__global__ __launch_bounds__(64) void k_nmscls(const float4* __restrict__ box4,
                                               const float* __restrict__ clsf,
                                               const float* __restrict__ topk_score,
                                               uint32_t* __restrict__ keepmask) {
  __shared__ float4 ob[CLS_CAP];
  __shared__ uint32_t rk[CLS_CAP];
  const int b = blockIdx.y;
  const int c = blockIdx.x;
  const int l = threadIdx.x;
  const float cf = (float)c;
  const float offv = cf * MAX_WH_;
  int n = 0;
  for (int chunk = 0; chunk < TOPK / 64; ++chunk) {
    int r = chunk * 64 + l;
    float s = topk_score[(size_t)b * TOPK + r];
    float cv = clsf[(size_t)b * TOPK + r];
    bool m = (s > CONF_T) && (cv == cf);
    unsigned long long mask = __ballot(m);
    if (m) {
      int pos = n + __popcll(mask & ((1ull << l) - 1ull));
      if (pos < CLS_CAP) {
        float4 bx = box4[(size_t)b * TOPK + r];
        ob[pos] = make_float4(__fadd_rn(bx.x, offv), __fadd_rn(bx.y, offv),
                              __fadd_rn(bx.z, offv), __fadd_rn(bx.w, offv));
        rk[pos] = (uint32_t)r;
      }
    }
    n += (int)__popcll(mask);
  }
  if (n > CLS_CAP) n = CLS_CAP;
  __syncthreads();
  float4 bj[4]; float aj[4];
#pragma unroll
  for (int t = 0; t < 4; ++t) {
    int j = l + 64 * t;
    if (j < n) {
      bj[t] = ob[j];
      aj[t] = __fmul_rn(__fsub_rn(bj[t].z, bj[t].x), __fsub_rn(bj[t].w, bj[t].y));
    }
  }
  uint32_t supp = 0, keptbits = 0;
  for (int i = 0; i < n; ++i) {
    int owner = i & 63, word = i >> 6;
    uint32_t so = (uint32_t)__shfl((int)supp, owner, 64);
    bool kept_i = !((so >> word) & 1u);
    if (l == owner && kept_i) keptbits |= 1u << word;
    if (kept_i) {
      float4 bi = ob[i];
      float a1 = __fmul_rn(__fsub_rn(bi.z, bi.x), __fsub_rn(bi.w, bi.y));
#pragma unroll
      for (int t = 0; t < 4; ++t) {
        int j = l + 64 * t;
        if (j > i && j < n && !((supp >> t) & 1u)) {
          float ltx = fmaxf(bi.x, bj[t].x), lty = fmaxf(bi.y, bj[t].y);
          float rbx = fminf(bi.z, bj[t].z), rby = fminf(bi.w, bj[t].w);
          float dx = fmaxf(__fsub_rn(rbx, ltx), 0.0f);
          float dy = fmaxf(__fsub_rn(rby, lty), 0.0f);
          float inter = __fmul_rn(dx, dy);
          float uni = __fsub_rn(__fadd_rn(a1, aj[t]), inter);
          if (inter > 0.0f && __fdiv_rn(inter, uni) > IOU_T) supp |= 1u << t;
        }
      }
    }
  }
#pragma unroll
  for (int t = 0; t < 4; ++t) {
    int j = l + 64 * t;
    if (j < n && ((keptbits >> t) & 1u)) {
      uint32_t r = rk[j];
      atomicOr(&keepmask[b * 64 + (r >> 5)], 1u << (r & 31));
    }
  }
}

__global__ __launch_bounds__(64) void k_out(const uint32_t* __restrict__ keepmask,
                                            const float4* __restrict__ box4,
                                            const float* __restrict__ topk_score,
                                            const float* __restrict__ clsf,
                                            float* __restrict__ out,
                                            float* __restrict__ out_counts) {
  const int b = blockIdx.x;
  const int l = threadIdx.x;
  float* ob = out + (size_t)b * MAXDET * 6;
  for (int t = l; t < MAXDET * 6; t += 64) ob[t] = 0.0f;
  __syncthreads();
  uint32_t w = keepmask[b * 64 + l];
  int pc = __popc(w);
  int pre = pc;
  for (int off = 1; off < 64; off <<= 1) {
    int v = __shfl_up(pre, off, 64);
    if (l >= off) pre += v;
  }
  if (l == 63) out_counts[b] = (float)pre;
  int r = pre - pc;
  for (int jj = 0; jj < 32; ++jj) {
    if ((w >> jj) & 1u) {
      if (r < MAXDET) {
        int k = l * 32 + jj;
        float4 bx = box4[(size_t)b * TOPK + k];
        float sc = topk_score[(size_t)b * TOPK + k];
        float cf = clsf[(size_t)b * TOPK + k];
        float* row = ob + (size_t)r * 6;
        row[0] = bx.x; row[1] = bx.y; row[2] = bx.z; row[3] = bx.w;
        row[4] = sc;   row[5] = cf;
      }
      ++r;
    }
  }
}

extern "C" void kernel_launch(void* const* d_in, const int* in_sizes, int n_in,
                              void* d_out, int out_size, void* d_ws, size_t ws_size,
                              hipStream_t stream) {
  const float* pred = (const float*)d_in[0];
  float* out = (float*)d_out;
  char* ws = (char*)d_ws;
  (void)in_sizes; (void)n_in; (void)out_size; (void)ws_size;

  void* args[] = {(void*)&pred, (void*)&ws, (void*)&out};
  hipError_t e = hipLaunchCooperativeKernel((const void*)k_all, dim3(GRID_),
                                            dim3(256), args, 0, stream);
  if (e == hipSuccess) return;
  (void)hipGetLastError();  // clear error state; use fallback pipeline

  uint32_t* hist1 = (uint32_t*)(ws + OFF_HIST1);
  uint32_t* keepmask = (uint32_t*)(ws + OFF_KEEP);
  uint32_t* cnt = (uint32_t*)(ws + OFF_CNT);
  float* topk_score = (float*)(ws + OFF_TSC);
  uint32_t* b1v = (uint32_t*)(ws + OFF_B1V);
  uint32_t* keys = (uint32_t*)(ws + OFF_KEYS);
  uint32_t* cls = (uint32_t*)(ws + OFF_CLS);
  unsigned long long* cand = (unsigned long long*)(ws + OFF_CAND);
  float4* box4 = (float4*)(ws + OFF_BOX4);
  float* clsf = (float*)(ws + OFF_CLSF);

  int n16 = ZERO_BYTES / 16;
  k_zero<<<(n16 + 255) / 256, 256, 0, stream>>>((uint4*)ws, n16);
  int grid_n = (B_ * N_ + 255) / 256;
  k_score<<<grid_n, 256, 0, stream>>>(pred, keys, cls, hist1);
  k_thresh<<<B_, 256, 0, stream>>>(hist1, b1v);
  dim3 cgrid((N_ + 255) / 256, B_);
  k_compact<<<cgrid, 256, 0, stream>>>(keys, b1v, cnt, cand);
  dim3 rgrid(CAP / 128, B_);
  k_rank<<<rgrid, 128, 0, stream>>>(pred, cls, cand, cnt, topk_score, box4, clsf);
  dim3 ngrid(NC_, B_);
  k_nmscls<<<ngrid, 64, 0, stream>>>(box4, clsf, topk_score, keepmask);
  k_out<<<B_, 64, 0, stream>>>(keepmask, box4, topk_score, clsf, out,
                               out + (size_t)B_ * MAXDET * 6);
}

// Round 11
// 138.618 us; speedup vs baseline: 3.4622x; 3.4622x over previous
//
#include <hip/hip_runtime.h>
#include <stdint.h>

#define B_ 16
#define N_ 25200
#define NC_ 80
#define TOPK 2048
#define MAXDET 300
#define CONF_T 0.25f
#define IOU_T 0.45f
#define MAX_WH_ 4096.0f
#define NBINS 4096
#define CAP 6144       // superset bound after level-1 threshold (~2.6k realistic)
#define CLS_CAP 256    // max candidates per class (data max ~45; 5x margin)
#define CNT_STRIDE 32  // pad counters to 128B
#define RANK_T 128     // threads per rank block

// ---------------- K0: zero hist1 + keepmask + cnt + topk_score + done ----------------
__global__ __launch_bounds__(256) void k_zero(uint4* __restrict__ p, int n16) {
  int i = blockIdx.x * 256 + threadIdx.x;
  if (i < n16) p[i] = make_uint4(0u, 0u, 0u, 0u);
}

// ---------------- K1: per-anchor score/class + level-1 histogram ----------------
// 256 threads <-> 256 anchors per block, 4 chunks of 64 anchors staged in LDS.
// 4 lanes/anchor, 20 classes each, shfl_xor merge with first-max tie rule.
// hist1 via LDS pre-aggregation (scores concentrate in ~30 hot bins).
__global__ __launch_bounds__(256) void k_score(const float* __restrict__ pred,
                                               uint32_t* __restrict__ keys,
                                               uint32_t* __restrict__ cls,
                                               uint32_t* __restrict__ hist1) {
  __shared__ float sh[64 * 85];
  __shared__ uint32_t lh[NBINS];
  const int tid = threadIdx.x;
  const int a = tid >> 2, ch = tid & 3;
  const int base_gid = blockIdx.x * 256;
  const int blk_b = base_gid / N_;
  const bool one_batch = (blk_b == (base_gid + 255) / N_);
  if (one_batch)
    for (int i = tid; i < NBINS; i += 256) lh[i] = 0;
  for (int chunk = 0; chunk < 4; ++chunk) {
    const float4* src =
        (const float4*)(pred + ((size_t)base_gid + chunk * 64) * 85);
    __syncthreads();  // prev chunk compute done (and lh zeroing visible)
    for (int i = tid; i < 64 * 85 / 4; i += 256) ((float4*)sh)[i] = src[i];
    __syncthreads();
    const int gid = base_gid + chunk * 64 + a;
    const float* row = sh + a * 85;
    const float obj = row[4];
    float best = -1.0f;
    int bj = 0;
#pragma unroll
    for (int i = 0; i < 20; ++i) {
      float v = row[5 + ch * 20 + i] * obj;  // plain mul, matches ref
      if (v > best) { best = v; bj = ch * 20 + i; }  // strict >: first max
    }
#pragma unroll
    for (int d = 1; d < 4; d <<= 1) {
      float vo = __shfl_xor(best, d, 64);
      int jo = __shfl_xor(bj, d, 64);
      if (vo > best || (vo == best && jo < bj)) { best = vo; bj = jo; }
    }
    if (ch == 0) {
      bool valid = (obj > CONF_T) && (best > CONF_T);
      float score = valid ? best : 0.0f;
      uint32_t key = __float_as_uint(score);  // score>=0: order-isomorphic
      keys[gid] = key;
      cls[gid] = (uint32_t)bj;
      if (score > CONF_T) {
        if (one_batch) atomicAdd(&lh[key >> 19], 1u);
        else atomicAdd(&hist1[(size_t)(gid / N_) * NBINS + (key >> 19)], 1u);
      }
    }
  }
  if (one_batch) {
    __syncthreads();
    for (int i = tid; i < NBINS; i += 256) {
      uint32_t cn = lh[i];
      if (cn) atomicAdd(&hist1[(size_t)blk_b * NBINS + i], cn);
    }
  }
}

// ---------------- K2: compact candidates (threshold fused, per-block redundant) ----------------
// Each block recomputes b1 = largest bin with suffix_count >= TOPK from hist1
// (identical result in every block; 16KB L2-resident read, latency hidden by
// 1584 blocks in flight). Then block-aggregated-atomic compaction of bins>=b1.
__global__ __launch_bounds__(256) void k_compact(const uint32_t* __restrict__ keys,
                                                 const uint32_t* __restrict__ hist1,
                                                 uint32_t* __restrict__ cnt,
                                                 unsigned long long* __restrict__ cand) {
  __shared__ uint32_t sums[256];
  __shared__ uint32_t s_b1, s_cnt, s_base;
  const int b = blockIdx.y;
  const int t = threadIdx.x;
  // --- fused level-1 threshold ---
  {
    const uint32_t* h = hist1 + (size_t)b * NBINS + t * 16;
    uint32_t v[16];
    uint32_t loc = 0;
#pragma unroll
    for (int i = 0; i < 16; ++i) { v[i] = h[i]; loc += v[i]; }
    sums[t] = loc;
    for (int d = 1; d < 256; d <<= 1) {
      __syncthreads();
      uint32_t y = (t + d < 256) ? sums[t + d] : 0;
      __syncthreads();
      sums[t] += y;
    }
    __syncthreads();
    const uint32_t need = TOPK;
    uint32_t above = (t + 1 < 256) ? sums[t + 1] : 0;
    if (above < need && sums[t] >= need) {  // exactly one crossing thread
      uint32_t cum = above;
      for (int i = 15; i >= 0; --i) {
        if (cum + v[i] >= need) { s_b1 = (uint32_t)(t * 16 + i); break; }
        cum += v[i];
      }
    }
    if (t == 0) {
      if (sums[0] < need) s_b1 = 1;  // <2048 valid: take all valid
      s_cnt = 0;
    }
  }
  __syncthreads();
  const uint32_t b1 = s_b1;
  // --- compaction ---
  const int n = blockIdx.x * 256 + t;
  uint32_t k = 0, loc = 0xFFFFFFFFu;
  if (n < N_) {
    k = keys[(size_t)b * N_ + n];
    if ((k >> 19) >= b1) loc = atomicAdd(&s_cnt, 1u);  // LDS atomic
  }
  __syncthreads();
  if (t == 0) s_base = atomicAdd(&cnt[b * CNT_STRIDE], s_cnt);
  __syncthreads();
  if (loc != 0xFFFFFFFFu) {
    uint32_t p = s_base + loc;
    if (p < CAP)
      cand[(size_t)b * CAP + p] = ((unsigned long long)k << 32) | (uint32_t)(~(uint32_t)n);
  }
}

// ---------------- K3: exact rank by counting + gather (grid-parallel) ----------------
// Keys are unique (low bits = ~idx) so rank_i = #{j: key_j > key_i} is exact and
// equals the position lax.top_k would assign. rank<TOPK -> emit at slot rank.
__global__ __launch_bounds__(RANK_T) void k_rank(const float* __restrict__ pred,
                                                 const uint32_t* __restrict__ cls,
                                                 const unsigned long long* __restrict__ cand,
                                                 const uint32_t* __restrict__ cnt,
                                                 float* __restrict__ topk_score,
                                                 float4* __restrict__ box4,
                                                 float* __restrict__ clsf) {
  __shared__ unsigned long long sh[CAP];
  const int b = blockIdx.y;
  int n = (int)cnt[b * CNT_STRIDE];
  if (n > CAP) n = CAP;
  const int own = blockIdx.x * RANK_T + threadIdx.x;
  if (blockIdx.x * RANK_T >= n) return;  // whole block idle (uniform exit)
  const unsigned long long* cb = cand + (size_t)b * CAP;
  for (int i = threadIdx.x; i < n; i += RANK_T) sh[i] = cb[i];
  __syncthreads();
  if (own >= n) return;
  const unsigned long long ki = sh[own];
  uint32_t rank = 0;
  int j = 0;
  for (; j + 8 <= n; j += 8) {
#pragma unroll
    for (int u = 0; u < 8; ++u) rank += (sh[j + u] > ki) ? 1u : 0u;
  }
  for (; j < n; ++j) rank += (sh[j] > ki) ? 1u : 0u;
  if (rank < TOPK) {
    uint32_t idx = ~((uint32_t)(ki & 0xFFFFFFFFull));
    topk_score[(size_t)b * TOPK + rank] = __uint_as_float((uint32_t)(ki >> 32));
    const float* p = pred + ((size_t)b * N_ + idx) * 85;
    float x = p[0], y = p[1], w = p[2], h = p[3];
    float hw = w * 0.5f, hh = h * 0.5f;  // exact (pow2 scale)
    box4[(size_t)b * TOPK + rank] = make_float4(x - hw, y - hh, x + hw, y + hh);
    clsf[(size_t)b * TOPK + rank] = (float)cls[(size_t)b * N_ + idx];
  }
}

// ---------------- K4: per-class greedy NMS + fused emit (last block/batch) ----------------
// Cross-class IoU is exactly 0 (class offset 4096 >> box extent), so the global
// rank-order greedy decomposes exactly into per-class scans. IoU math replicates
// the reference bit-for-bit INCLUDING offset-box rounding. The 80th (last
// finishing) block of each batch emits the output rows; result depends only on
// the complete keepmask -> deterministic.
__global__ __launch_bounds__(64) void k_nmscls(const float4* __restrict__ box4,
                                               const float* __restrict__ clsf,
                                               const float* __restrict__ topk_score,
                                               uint32_t* __restrict__ keepmask,
                                               uint32_t* __restrict__ done,
                                               float* __restrict__ out,
                                               float* __restrict__ out_counts) {
  __shared__ float4 ob[CLS_CAP];
  __shared__ uint32_t rk[CLS_CAP];
  const int b = blockIdx.y;
  const int c = blockIdx.x;
  const int l = threadIdx.x;
  const float cf = (float)c;
  const float offv = cf * MAX_WH_;  // exact (pow2 scale)
  int n = 0;
  for (int chunk = 0; chunk < TOPK / 64; ++chunk) {
    int r = chunk * 64 + l;
    float s = topk_score[(size_t)b * TOPK + r];
    float cv = clsf[(size_t)b * TOPK + r];
    bool m = (s > CONF_T) && (cv == cf);
    unsigned long long mask = __ballot(m);
    if (m) {
      int pos = n + __popcll(mask & ((1ull << l) - 1ull));
      if (pos < CLS_CAP) {
        float4 bx = box4[(size_t)b * TOPK + r];
        ob[pos] = make_float4(__fadd_rn(bx.x, offv), __fadd_rn(bx.y, offv),
                              __fadd_rn(bx.z, offv), __fadd_rn(bx.w, offv));
        rk[pos] = (uint32_t)r;
      }
    }
    n += (int)__popcll(mask);
  }
  if (n > CLS_CAP) n = CLS_CAP;
  __syncthreads();
  float4 bj[4]; float aj[4];
#pragma unroll
  for (int t = 0; t < 4; ++t) {
    int j = l + 64 * t;
    if (j < n) {
      bj[t] = ob[j];
      aj[t] = __fmul_rn(__fsub_rn(bj[t].z, bj[t].x), __fsub_rn(bj[t].w, bj[t].y));
    }
  }
  uint32_t supp = 0, keptbits = 0;
  for (int i = 0; i < n; ++i) {
    int owner = i & 63, word = i >> 6;
    uint32_t so = (uint32_t)__shfl((int)supp, owner, 64);
    bool kept_i = !((so >> word) & 1u);
    if (l == owner && kept_i) keptbits |= 1u << word;
    if (kept_i) {
      float4 bi = ob[i];
      float a1 = __fmul_rn(__fsub_rn(bi.z, bi.x), __fsub_rn(bi.w, bi.y));
#pragma unroll
      for (int t = 0; t < 4; ++t) {
        int j = l + 64 * t;
        if (j > i && j < n && !((supp >> t) & 1u)) {
          float ltx = fmaxf(bi.x, bj[t].x), lty = fmaxf(bi.y, bj[t].y);
          float rbx = fminf(bi.z, bj[t].z), rby = fminf(bi.w, bj[t].w);
          float dx = fmaxf(__fsub_rn(rbx, ltx), 0.0f);
          float dy = fmaxf(__fsub_rn(rby, lty), 0.0f);
          float inter = __fmul_rn(dx, dy);
          float uni = __fsub_rn(__fadd_rn(a1, aj[t]), inter);
          if (inter > 0.0f && __fdiv_rn(inter, uni) > IOU_T) supp |= 1u << t;
        }
      }
    }
  }
#pragma unroll
  for (int t = 0; t < 4; ++t) {
    int j = l + 64 * t;
    if (j < n && ((keptbits >> t) & 1u)) {
      uint32_t r = rk[j];
      atomicOr(&keepmask[b * 64 + (r >> 5)], 1u << (r & 31));
    }
  }
  // ---- last-block-per-batch emits the output ----
  __threadfence();  // publish our keepmask bits before signaling
  uint32_t old = 0;
  if (l == 0) old = atomicAdd(&done[b * 16], 1u);
  old = (uint32_t)__shfl((int)old, 0, 64);
  if (old == NC_ - 1) {
    __threadfence();  // acquire: other blocks' keepmask writes visible
    float* ob_ = out + (size_t)b * MAXDET * 6;
    for (int t = l; t < MAXDET * 6; t += 64) ob_[t] = 0.0f;
    __syncthreads();  // single wave: drains stores before refill
    uint32_t w = keepmask[b * 64 + l];
    int pc = __popc(w);
    int pre = pc;
    for (int off = 1; off < 64; off <<= 1) {
      int v = __shfl_up(pre, off, 64);
      if (l >= off) pre += v;
    }
    if (l == 63) out_counts[b] = (float)pre;  // total kept
    int r = pre - pc;  // exclusive prefix of kept counts
    for (int jj = 0; jj < 32; ++jj) {
      if ((w >> jj) & 1u) {
        if (r < MAXDET) {
          int k = l * 32 + jj;
          float4 bx = box4[(size_t)b * TOPK + k];
          float sc = topk_score[(size_t)b * TOPK + k];
          float cfv = clsf[(size_t)b * TOPK + k];
          float* row = ob_ + (size_t)r * 6;
          row[0] = bx.x; row[1] = bx.y; row[2] = bx.z; row[3] = bx.w;
          row[4] = sc;   row[5] = cfv;
        }
        ++r;
      }
    }
  }
}

extern "C" void kernel_launch(void* const* d_in, const int* in_sizes, int n_in,
                              void* d_out, int out_size, void* d_ws, size_t ws_size,
                              hipStream_t stream) {
  const float* pred = (const float*)d_in[0];
  float* out = (float*)d_out;

  char* ws = (char*)d_ws;
  size_t off = 0;
  // --- zeroed-each-launch region (contiguous) ---
  uint32_t* hist1 = (uint32_t*)(ws + off); off += (size_t)B_ * NBINS * 4;        // 256 KB
  uint32_t* keepmask = (uint32_t*)(ws + off); off += (size_t)B_ * 64 * 4;        // 4 KB
  uint32_t* cnt   = (uint32_t*)(ws + off); off += (size_t)B_ * CNT_STRIDE * 4;   // 2 KB
  float* topk_score = (float*)(ws + off);  off += (size_t)B_ * TOPK * 4;         // 128 KB
  uint32_t* done  = (uint32_t*)(ws + off); off += (size_t)B_ * 16 * 4;           // 1 KB
  size_t zero_bytes = off;
  // --- rest ---
  uint32_t* keys = (uint32_t*)(ws + off); off += (size_t)B_ * N_ * 4;            // 1.6 MB
  uint32_t* cls = (uint32_t*)(ws + off);  off += (size_t)B_ * N_ * 4;            // 1.6 MB
  unsigned long long* cand = (unsigned long long*)(ws + off); off += (size_t)B_ * CAP * 8;  // 786 KB
  float4* box4 = (float4*)(ws + off);      off += (size_t)B_ * TOPK * 16;        // 512 KB
  float* clsf = (float*)(ws + off);        off += (size_t)B_ * TOPK * 4;         // 128 KB

  (void)in_sizes; (void)n_in; (void)out_size; (void)ws_size;

  int n16 = (int)(zero_bytes / 16);
  k_zero<<<(n16 + 255) / 256, 256, 0, stream>>>((uint4*)ws, n16);
  int grid_n = (B_ * N_ + 255) / 256;
  k_score<<<grid_n, 256, 0, stream>>>(pred, keys, cls, hist1);
  dim3 cgrid((N_ + 255) / 256, B_);
  k_compact<<<cgrid, 256, 0, stream>>>(keys, hist1, cnt, cand);
  dim3 rgrid(CAP / RANK_T, B_);
  k_rank<<<rgrid, RANK_T, 0, stream>>>(pred, cls, cand, cnt, topk_score, box4, clsf);
  dim3 ngrid(NC_, B_);
  k_nmscls<<<ngrid, 64, 0, stream>>>(box4, clsf, topk_score, keepmask, done,
                                     out, out + (size_t)B_ * MAXDET * 6);
}

// Round 12
// 138.282 us; speedup vs baseline: 3.4706x; 1.0024x over previous
//
#include <hip/hip_runtime.h>
#include <stdint.h>

#define B_ 16
#define N_ 25200
#define NC_ 80
#define TOPK 2048
#define MAXDET 300
#define CONF_T 0.25f
#define IOU_T 0.45f
#define MAX_WH_ 4096.0f
#define NBINS 4096
#define CAP 6144       // superset bound after level-1 threshold (~2.6k realistic)
#define CLS_CAP 256    // max candidates per class (data max ~45; 5x margin)
#define CNT_STRIDE 32  // pad counters to 128B
#define RANK_T 128     // threads per rank block

// ---------------- K0: zero hist1 + keepmask + cnt + topk_score + done ----------------
__global__ __launch_bounds__(256) void k_zero(uint4* __restrict__ p, int n16) {
  int i = blockIdx.x * 256 + threadIdx.x;
  if (i < n16) p[i] = make_uint4(0u, 0u, 0u, 0u);
}

// ---------------- K1: per-anchor score/class + level-1 histogram ----------------
// 256 threads <-> 256 anchors per block, 4 chunks of 64 anchors staged in LDS.
// 4 lanes/anchor, 20 classes each, shfl_xor merge with first-max tie rule.
// hist1 via LDS pre-aggregation (scores concentrate in ~30 hot bins).
__global__ __launch_bounds__(256) void k_score(const float* __restrict__ pred,
                                               uint32_t* __restrict__ keys,
                                               uint32_t* __restrict__ cls,
                                               uint32_t* __restrict__ hist1) {
  __shared__ float sh[64 * 85];
  __shared__ uint32_t lh[NBINS];
  const int tid = threadIdx.x;
  const int a = tid >> 2, ch = tid & 3;
  const int base_gid = blockIdx.x * 256;
  const int blk_b = base_gid / N_;
  const bool one_batch = (blk_b == (base_gid + 255) / N_);
  if (one_batch)
    for (int i = tid; i < NBINS; i += 256) lh[i] = 0;
  for (int chunk = 0; chunk < 4; ++chunk) {
    const float4* src =
        (const float4*)(pred + ((size_t)base_gid + chunk * 64) * 85);
    __syncthreads();  // prev chunk compute done (and lh zeroing visible)
    for (int i = tid; i < 64 * 85 / 4; i += 256) ((float4*)sh)[i] = src[i];
    __syncthreads();
    const int gid = base_gid + chunk * 64 + a;
    const float* row = sh + a * 85;
    const float obj = row[4];
    float best = -1.0f;
    int bj = 0;
#pragma unroll
    for (int i = 0; i < 20; ++i) {
      float v = row[5 + ch * 20 + i] * obj;  // plain mul, matches ref
      if (v > best) { best = v; bj = ch * 20 + i; }  // strict >: first max
    }
#pragma unroll
    for (int d = 1; d < 4; d <<= 1) {
      float vo = __shfl_xor(best, d, 64);
      int jo = __shfl_xor(bj, d, 64);
      if (vo > best || (vo == best && jo < bj)) { best = vo; bj = jo; }
    }
    if (ch == 0) {
      bool valid = (obj > CONF_T) && (best > CONF_T);
      float score = valid ? best : 0.0f;
      uint32_t key = __float_as_uint(score);  // score>=0: order-isomorphic
      keys[gid] = key;
      cls[gid] = (uint32_t)bj;
      if (score > CONF_T) {
        if (one_batch) atomicAdd(&lh[key >> 19], 1u);
        else atomicAdd(&hist1[(size_t)(gid / N_) * NBINS + (key >> 19)], 1u);
      }
    }
  }
  if (one_batch) {
    __syncthreads();
    for (int i = tid; i < NBINS; i += 256) {
      uint32_t cn = lh[i];
      if (cn) atomicAdd(&hist1[(size_t)blk_b * NBINS + i], cn);
    }
  }
}

// ---------------- K2: level-1 threshold (one block/batch) ----------------
__global__ __launch_bounds__(256) void k_thresh(const uint32_t* __restrict__ hist,
                                                uint32_t* __restrict__ b_out) {
  __shared__ uint32_t sums[256];
  const int b = blockIdx.x;
  const int t = threadIdx.x;
  const uint32_t* h = hist + (size_t)b * NBINS + t * 16;
  uint32_t v[16];
  uint32_t loc = 0;
#pragma unroll
  for (int i = 0; i < 16; ++i) { v[i] = h[i]; loc += v[i]; }
  sums[t] = loc;
  for (int d = 1; d < 256; d <<= 1) {
    __syncthreads();
    uint32_t y = (t + d < 256) ? sums[t + d] : 0;
    __syncthreads();
    sums[t] += y;
  }
  __syncthreads();
  const uint32_t need = TOPK;
  uint32_t above = (t + 1 < 256) ? sums[t + 1] : 0;
  if (above < need && sums[t] >= need) {  // exactly one crossing thread
    uint32_t cum = above;
    for (int i = 15; i >= 0; --i) {
      if (cum + v[i] >= need) { b_out[b] = (uint32_t)(t * 16 + i); break; }
      cum += v[i];
    }
  }
  if (t == 0 && sums[0] < need) b_out[b] = 1;  // <2048 valid: take all valid
}

// ---------------- K3: compact candidates (block-aggregated atomics) ----------------
__global__ __launch_bounds__(256) void k_compact(const uint32_t* __restrict__ keys,
                                                 const uint32_t* __restrict__ b1v,
                                                 uint32_t* __restrict__ cnt,
                                                 unsigned long long* __restrict__ cand) {
  __shared__ uint32_t s_cnt, s_base;
  const int b = blockIdx.y;
  const int n = blockIdx.x * 256 + threadIdx.x;
  if (threadIdx.x == 0) s_cnt = 0;
  __syncthreads();
  uint32_t k = 0, loc = 0xFFFFFFFFu;
  if (n < N_) {
    k = keys[(size_t)b * N_ + n];
    if ((k >> 19) >= b1v[b]) loc = atomicAdd(&s_cnt, 1u);  // LDS atomic
  }
  __syncthreads();
  if (threadIdx.x == 0) s_base = atomicAdd(&cnt[b * CNT_STRIDE], s_cnt);
  __syncthreads();
  if (loc != 0xFFFFFFFFu) {
    uint32_t p = s_base + loc;
    if (p < CAP)
      cand[(size_t)b * CAP + p] = ((unsigned long long)k << 32) | (uint32_t)(~(uint32_t)n);
  }
}

// ---------------- K4: exact rank by counting + gather (grid-parallel) ----------------
// Keys are unique (low bits = ~idx) so rank_i = #{j: key_j > key_i} is exact and
// equals the position lax.top_k would assign. rank<TOPK -> emit at slot rank.
__global__ __launch_bounds__(RANK_T) void k_rank(const float* __restrict__ pred,
                                                 const uint32_t* __restrict__ cls,
                                                 const unsigned long long* __restrict__ cand,
                                                 const uint32_t* __restrict__ cnt,
                                                 float* __restrict__ topk_score,
                                                 float4* __restrict__ box4,
                                                 float* __restrict__ clsf) {
  __shared__ unsigned long long sh[CAP];
  const int b = blockIdx.y;
  int n = (int)cnt[b * CNT_STRIDE];
  if (n > CAP) n = CAP;
  const int own = blockIdx.x * RANK_T + threadIdx.x;
  if (blockIdx.x * RANK_T >= n) return;  // whole block idle (uniform exit)
  const unsigned long long* cb = cand + (size_t)b * CAP;
  for (int i = threadIdx.x; i < n; i += RANK_T) sh[i] = cb[i];
  __syncthreads();
  if (own >= n) return;
  const unsigned long long ki = sh[own];
  uint32_t rank = 0;
  int j = 0;
  for (; j + 8 <= n; j += 8) {
#pragma unroll
    for (int u = 0; u < 8; ++u) rank += (sh[j + u] > ki) ? 1u : 0u;
  }
  for (; j < n; ++j) rank += (sh[j] > ki) ? 1u : 0u;
  if (rank < TOPK) {
    uint32_t idx = ~((uint32_t)(ki & 0xFFFFFFFFull));
    topk_score[(size_t)b * TOPK + rank] = __uint_as_float((uint32_t)(ki >> 32));
    const float* p = pred + ((size_t)b * N_ + idx) * 85;
    float x = p[0], y = p[1], w = p[2], h = p[3];
    float hw = w * 0.5f, hh = h * 0.5f;  // exact (pow2 scale)
    box4[(size_t)b * TOPK + rank] = make_float4(x - hw, y - hh, x + hw, y + hh);
    clsf[(size_t)b * TOPK + rank] = (float)cls[(size_t)b * N_ + idx];
  }
}

// ---------------- K5: per-class greedy NMS + fused emit (last block/batch) ----------------
// Cross-class IoU is exactly 0 (class offset 4096 >> box extent), so the global
// rank-order greedy decomposes exactly into per-class scans. IoU math replicates
// the reference bit-for-bit INCLUDING offset-box rounding. The last-finishing
// block of each batch emits the output; it reads keepmask via atomicOr(.,0)
// (device-coherent) since writers are concurrent blocks on other XCDs.
__global__ __launch_bounds__(64) void k_nmscls(const float4* __restrict__ box4,
                                               const float* __restrict__ clsf,
                                               const float* __restrict__ topk_score,
                                               uint32_t* __restrict__ keepmask,
                                               uint32_t* __restrict__ done,
                                               float* __restrict__ out,
                                               float* __restrict__ out_counts) {
  __shared__ float4 ob[CLS_CAP];
  __shared__ uint32_t rk[CLS_CAP];
  const int b = blockIdx.y;
  const int c = blockIdx.x;
  const int l = threadIdx.x;
  const float cf = (float)c;
  const float offv = cf * MAX_WH_;  // exact (pow2 scale)
  int n = 0;
  for (int chunk = 0; chunk < TOPK / 64; ++chunk) {
    int r = chunk * 64 + l;
    float s = topk_score[(size_t)b * TOPK + r];
    float cv = clsf[(size_t)b * TOPK + r];
    bool m = (s > CONF_T) && (cv == cf);
    unsigned long long mask = __ballot(m);
    if (m) {
      int pos = n + __popcll(mask & ((1ull << l) - 1ull));
      if (pos < CLS_CAP) {
        float4 bx = box4[(size_t)b * TOPK + r];
        ob[pos] = make_float4(__fadd_rn(bx.x, offv), __fadd_rn(bx.y, offv),
                              __fadd_rn(bx.z, offv), __fadd_rn(bx.w, offv));
        rk[pos] = (uint32_t)r;
      }
    }
    n += (int)__popcll(mask);
  }
  if (n > CLS_CAP) n = CLS_CAP;
  __syncthreads();
  float4 bj[4]; float aj[4];
#pragma unroll
  for (int t = 0; t < 4; ++t) {
    int j = l + 64 * t;
    if (j < n) {
      bj[t] = ob[j];
      aj[t] = __fmul_rn(__fsub_rn(bj[t].z, bj[t].x), __fsub_rn(bj[t].w, bj[t].y));
    }
  }
  uint32_t supp = 0, keptbits = 0;
  for (int i = 0; i < n; ++i) {
    int owner = i & 63, word = i >> 6;
    uint32_t so = (uint32_t)__shfl((int)supp, owner, 64);
    bool kept_i = !((so >> word) & 1u);
    if (l == owner && kept_i) keptbits |= 1u << word;
    if (kept_i) {
      float4 bi = ob[i];
      float a1 = __fmul_rn(__fsub_rn(bi.z, bi.x), __fsub_rn(bi.w, bi.y));
#pragma unroll
      for (int t = 0; t < 4; ++t) {
        int j = l + 64 * t;
        if (j > i && j < n && !((supp >> t) & 1u)) {
          float ltx = fmaxf(bi.x, bj[t].x), lty = fmaxf(bi.y, bj[t].y);
          float rbx = fminf(bi.z, bj[t].z), rby = fminf(bi.w, bj[t].w);
          float dx = fmaxf(__fsub_rn(rbx, ltx), 0.0f);
          float dy = fmaxf(__fsub_rn(rby, lty), 0.0f);
          float inter = __fmul_rn(dx, dy);
          float uni = __fsub_rn(__fadd_rn(a1, aj[t]), inter);
          if (inter > 0.0f && __fdiv_rn(inter, uni) > IOU_T) supp |= 1u << t;
        }
      }
    }
  }
#pragma unroll
  for (int t = 0; t < 4; ++t) {
    int j = l + 64 * t;
    if (j < n && ((keptbits >> t) & 1u)) {
      uint32_t r = rk[j];
      atomicOr(&keepmask[b * 64 + (r >> 5)], 1u << (r & 31));
    }
  }
  // ---- last-block-per-batch emits the output ----
  __threadfence();  // publish our keepmask bits before signaling
  uint32_t old = 0;
  if (l == 0) old = atomicAdd(&done[b * 16], 1u);
  old = (uint32_t)__shfl((int)old, 0, 64);
  if (old == NC_ - 1) {
    float* ob_ = out + (size_t)b * MAXDET * 6;
    for (int t = l; t < MAXDET * 6; t += 64) ob_[t] = 0.0f;
    __syncthreads();  // single wave: drain zero-fill before row writes
    uint32_t w = atomicOr(&keepmask[b * 64 + l], 0u);  // device-coherent read
    int pc = __popc(w);
    int pre = pc;
    for (int off = 1; off < 64; off <<= 1) {
      int v = __shfl_up(pre, off, 64);
      if (l >= off) pre += v;
    }
    if (l == 63) out_counts[b] = (float)pre;  // total kept
    int r = pre - pc;  // exclusive prefix of kept counts
    for (int jj = 0; jj < 32; ++jj) {
      if ((w >> jj) & 1u) {
        if (r < MAXDET) {
          int k = l * 32 + jj;
          float4 bx = box4[(size_t)b * TOPK + k];
          float sc = topk_score[(size_t)b * TOPK + k];
          float cfv = clsf[(size_t)b * TOPK + k];
          float* row = ob_ + (size_t)r * 6;
          row[0] = bx.x; row[1] = bx.y; row[2] = bx.z; row[3] = bx.w;
          row[4] = sc;   row[5] = cfv;
        }
        ++r;
      }
    }
  }
}

extern "C" void kernel_launch(void* const* d_in, const int* in_sizes, int n_in,
                              void* d_out, int out_size, void* d_ws, size_t ws_size,
                              hipStream_t stream) {
  const float* pred = (const float*)d_in[0];
  float* out = (float*)d_out;

  char* ws = (char*)d_ws;
  size_t off = 0;
  // --- zeroed-each-launch region (contiguous) ---
  uint32_t* hist1 = (uint32_t*)(ws + off); off += (size_t)B_ * NBINS * 4;        // 256 KB
  uint32_t* keepmask = (uint32_t*)(ws + off); off += (size_t)B_ * 64 * 4;        // 4 KB
  uint32_t* cnt   = (uint32_t*)(ws + off); off += (size_t)B_ * CNT_STRIDE * 4;   // 2 KB
  float* topk_score = (float*)(ws + off);  off += (size_t)B_ * TOPK * 4;         // 128 KB
  uint32_t* done  = (uint32_t*)(ws + off); off += (size_t)B_ * 16 * 4;           // 1 KB
  size_t zero_bytes = off;
  // --- rest ---
  uint32_t* b1v   = (uint32_t*)(ws + off); off += 64;
  uint32_t* keys = (uint32_t*)(ws + off); off += (size_t)B_ * N_ * 4;            // 1.6 MB
  uint32_t* cls = (uint32_t*)(ws + off);  off += (size_t)B_ * N_ * 4;            // 1.6 MB
  unsigned long long* cand = (unsigned long long*)(ws + off); off += (size_t)B_ * CAP * 8;  // 786 KB
  float4* box4 = (float4*)(ws + off);      off += (size_t)B_ * TOPK * 16;        // 512 KB
  float* clsf = (float*)(ws + off);        off += (size_t)B_ * TOPK * 4;         // 128 KB

  (void)in_sizes; (void)n_in; (void)out_size; (void)ws_size;

  int n16 = (int)(zero_bytes / 16);
  k_zero<<<(n16 + 255) / 256, 256, 0, stream>>>((uint4*)ws, n16);
  int grid_n = (B_ * N_ + 255) / 256;
  k_score<<<grid_n, 256, 0, stream>>>(pred, keys, cls, hist1);
  k_thresh<<<B_, 256, 0, stream>>>(hist1, b1v);
  dim3 cgrid((N_ + 255) / 256, B_);
  k_compact<<<cgrid, 256, 0, stream>>>(keys, b1v, cnt, cand);
  dim3 rgrid(CAP / RANK_T, B_);
  k_rank<<<rgrid, RANK_T, 0, stream>>>(pred, cls, cand, cnt, topk_score, box4, clsf);
  dim3 ngrid(NC_, B_);
  k_nmscls<<<ngrid, 64, 0, stream>>>(box4, clsf, topk_score, keepmask, done,
                                     out, out + (size_t)B_ * MAXDET * 6);
}

// Round 13
// 122.090 us; speedup vs baseline: 3.9309x; 1.1326x over previous
//
#include <hip/hip_runtime.h>
#include <stdint.h>

#define B_ 16
#define N_ 25200
#define NC_ 80
#define TOPK 2048
#define MAXDET 300
#define CONF_T 0.25f
#define IOU_T 0.45f
#define MAX_WH_ 4096.0f
#define NBINS 4096
#define CAP 6144       // superset bound after level-1 threshold (~2.6k realistic)
#define CLS_CAP 256    // max candidates per class (data max ~45; 5x margin)
#define CNT_STRIDE 32  // pad counters to 128B
#define RANK_T 128     // threads per rank block
#define LH_BASE 2000   // score>0.25 => key>>19 in [2000,2032] (fp32 bit layout)
#define LH_N 64

// ---------------- K0: zero hist1 + keepmask + cnt + topk_score ----------------
__global__ __launch_bounds__(256) void k_zero(uint4* __restrict__ p, int n16) {
  int i = blockIdx.x * 256 + threadIdx.x;
  if (i < n16) p[i] = make_uint4(0u, 0u, 0u, 0u);
}

// ---------------- K1: per-anchor score/class + level-1 histogram ----------------
// 256 threads <-> 256 anchors per block, 4 chunks of 64 anchors staged in LDS.
// 4 lanes/anchor, 20 classes each, shfl_xor merge with first-max tie rule.
// LDS histogram is 64 entries (valid-score bins provably in [2000,2032]):
// 22KB LDS/block -> 7 blocks/CU occupancy on this BW-bound stream.
__global__ __launch_bounds__(256) void k_score(const float* __restrict__ pred,
                                               uint32_t* __restrict__ keys,
                                               uint32_t* __restrict__ cls,
                                               uint32_t* __restrict__ hist1) {
  __shared__ float sh[64 * 85];
  __shared__ uint32_t lh[LH_N];
  const int tid = threadIdx.x;
  const int a = tid >> 2, ch = tid & 3;
  const int base_gid = blockIdx.x * 256;
  const int blk_b = base_gid / N_;
  const bool one_batch = (blk_b == (base_gid + 255) / N_);
  if (one_batch && tid < LH_N) lh[tid] = 0;
  for (int chunk = 0; chunk < 4; ++chunk) {
    const float4* src =
        (const float4*)(pred + ((size_t)base_gid + chunk * 64) * 85);
    __syncthreads();  // prev chunk compute done (and lh zeroing visible)
    for (int i = tid; i < 64 * 85 / 4; i += 256) ((float4*)sh)[i] = src[i];
    __syncthreads();
    const int gid = base_gid + chunk * 64 + a;
    const float* row = sh + a * 85;
    const float obj = row[4];
    float best = -1.0f;
    int bj = 0;
#pragma unroll
    for (int i = 0; i < 20; ++i) {
      float v = row[5 + ch * 20 + i] * obj;  // plain mul, matches ref
      if (v > best) { best = v; bj = ch * 20 + i; }  // strict >: first max
    }
#pragma unroll
    for (int d = 1; d < 4; d <<= 1) {
      float vo = __shfl_xor(best, d, 64);
      int jo = __shfl_xor(bj, d, 64);
      if (vo > best || (vo == best && jo < bj)) { best = vo; bj = jo; }
    }
    if (ch == 0) {
      bool valid = (obj > CONF_T) && (best > CONF_T);
      float score = valid ? best : 0.0f;
      uint32_t key = __float_as_uint(score);  // score>=0: order-isomorphic
      keys[gid] = key;
      cls[gid] = (uint32_t)bj;
      if (score > CONF_T) {  // implies (key>>19) in [2000,2032]
        if (one_batch) atomicAdd(&lh[(key >> 19) - LH_BASE], 1u);
        else atomicAdd(&hist1[(size_t)(gid / N_) * NBINS + (key >> 19)], 1u);
      }
    }
  }
  if (one_batch) {
    __syncthreads();
    if (tid < LH_N) {
      uint32_t cn = lh[tid];
      if (cn) atomicAdd(&hist1[(size_t)blk_b * NBINS + LH_BASE + tid], cn);
    }
  }
}

// ---------------- K2: level-1 threshold (one block/batch) ----------------
__global__ __launch_bounds__(256) void k_thresh(const uint32_t* __restrict__ hist,
                                                uint32_t* __restrict__ b_out) {
  __shared__ uint32_t sums[256];
  const int b = blockIdx.x;
  const int t = threadIdx.x;
  const uint32_t* h = hist + (size_t)b * NBINS + t * 16;
  uint32_t v[16];
  uint32_t loc = 0;
#pragma unroll
  for (int i = 0; i < 16; ++i) { v[i] = h[i]; loc += v[i]; }
  sums[t] = loc;
  for (int d = 1; d < 256; d <<= 1) {
    __syncthreads();
    uint32_t y = (t + d < 256) ? sums[t + d] : 0;
    __syncthreads();
    sums[t] += y;
  }
  __syncthreads();
  const uint32_t need = TOPK;
  uint32_t above = (t + 1 < 256) ? sums[t + 1] : 0;
  if (above < need && sums[t] >= need) {  // exactly one crossing thread
    uint32_t cum = above;
    for (int i = 15; i >= 0; --i) {
      if (cum + v[i] >= need) { b_out[b] = (uint32_t)(t * 16 + i); break; }
      cum += v[i];
    }
  }
  if (t == 0 && sums[0] < need) b_out[b] = 1;  // <2048 valid: take all valid
}

// ---------------- K3: compact candidates (block-aggregated atomics) ----------------
__global__ __launch_bounds__(256) void k_compact(const uint32_t* __restrict__ keys,
                                                 const uint32_t* __restrict__ b1v,
                                                 uint32_t* __restrict__ cnt,
                                                 unsigned long long* __restrict__ cand) {
  __shared__ uint32_t s_cnt, s_base;
  const int b = blockIdx.y;
  const int n = blockIdx.x * 256 + threadIdx.x;
  if (threadIdx.x == 0) s_cnt = 0;
  __syncthreads();
  uint32_t k = 0, loc = 0xFFFFFFFFu;
  if (n < N_) {
    k = keys[(size_t)b * N_ + n];
    if ((k >> 19) >= b1v[b]) loc = atomicAdd(&s_cnt, 1u);  // LDS atomic
  }
  __syncthreads();
  if (threadIdx.x == 0) s_base = atomicAdd(&cnt[b * CNT_STRIDE], s_cnt);
  __syncthreads();
  if (loc != 0xFFFFFFFFu) {
    uint32_t p = s_base + loc;
    if (p < CAP)
      cand[(size_t)b * CAP + p] = ((unsigned long long)k << 32) | (uint32_t)(~(uint32_t)n);
  }
}

// ---------------- K4: exact rank by counting + gather (grid-parallel) ----------------
// Keys are unique (low bits = ~idx) so rank_i = #{j: key_j > key_i} is exact and
// equals the position lax.top_k would assign. rank<TOPK -> emit at slot rank.
__global__ __launch_bounds__(RANK_T) void k_rank(const float* __restrict__ pred,
                                                 const uint32_t* __restrict__ cls,
                                                 const unsigned long long* __restrict__ cand,
                                                 const uint32_t* __restrict__ cnt,
                                                 float* __restrict__ topk_score,
                                                 float4* __restrict__ box4,
                                                 float* __restrict__ clsf) {
  __shared__ unsigned long long sh[CAP];
  const int b = blockIdx.y;
  int n = (int)cnt[b * CNT_STRIDE];
  if (n > CAP) n = CAP;
  const int own = blockIdx.x * RANK_T + threadIdx.x;
  if (blockIdx.x * RANK_T >= n) return;  // whole block idle (uniform exit)
  const unsigned long long* cb = cand + (size_t)b * CAP;
  for (int i = threadIdx.x; i < n; i += RANK_T) sh[i] = cb[i];
  __syncthreads();
  if (own >= n) return;
  const unsigned long long ki = sh[own];
  uint32_t rank = 0;
  int j = 0;
  for (; j + 8 <= n; j += 8) {
#pragma unroll
    for (int u = 0; u < 8; ++u) rank += (sh[j + u] > ki) ? 1u : 0u;
  }
  for (; j < n; ++j) rank += (sh[j] > ki) ? 1u : 0u;
  if (rank < TOPK) {
    uint32_t idx = ~((uint32_t)(ki & 0xFFFFFFFFull));
    topk_score[(size_t)b * TOPK + rank] = __uint_as_float((uint32_t)(ki >> 32));
    const float* p = pred + ((size_t)b * N_ + idx) * 85;
    float x = p[0], y = p[1], w = p[2], h = p[3];
    float hw = w * 0.5f, hh = h * 0.5f;  // exact (pow2 scale)
    box4[(size_t)b * TOPK + rank] = make_float4(x - hw, y - hh, x + hw, y + hh);
    clsf[(size_t)b * TOPK + rank] = (float)cls[(size_t)b * N_ + idx];
  }
}

// ---------------- K5: per-class greedy NMS (one wave per (batch,class)) ----------------
// Cross-class IoU is exactly 0 (class offset 4096 >> box extent), so the global
// rank-order greedy decomposes exactly into per-class scans. IoU math replicates
// the reference bit-for-bit INCLUDING offset-box rounding.
__global__ __launch_bounds__(64) void k_nmscls(const float4* __restrict__ box4,
                                               const float* __restrict__ clsf,
                                               const float* __restrict__ topk_score,
                                               uint32_t* __restrict__ keepmask) {
  __shared__ float4 ob[CLS_CAP];
  __shared__ uint32_t rk[CLS_CAP];
  const int b = blockIdx.y;
  const int c = blockIdx.x;
  const int l = threadIdx.x;
  const float cf = (float)c;
  const float offv = cf * MAX_WH_;  // exact (pow2 scale)
  int n = 0;
  for (int chunk = 0; chunk < TOPK / 64; ++chunk) {
    int r = chunk * 64 + l;
    float s = topk_score[(size_t)b * TOPK + r];
    float cv = clsf[(size_t)b * TOPK + r];
    bool m = (s > CONF_T) && (cv == cf);
    unsigned long long mask = __ballot(m);
    if (m) {
      int pos = n + __popcll(mask & ((1ull << l) - 1ull));
      if (pos < CLS_CAP) {
        float4 bx = box4[(size_t)b * TOPK + r];
        ob[pos] = make_float4(__fadd_rn(bx.x, offv), __fadd_rn(bx.y, offv),
                              __fadd_rn(bx.z, offv), __fadd_rn(bx.w, offv));
        rk[pos] = (uint32_t)r;
      }
    }
    n += (int)__popcll(mask);
  }
  if (n > CLS_CAP) n = CLS_CAP;
  __syncthreads();
  float4 bj[4]; float aj[4];
#pragma unroll
  for (int t = 0; t < 4; ++t) {
    int j = l + 64 * t;
    if (j < n) {
      bj[t] = ob[j];
      aj[t] = __fmul_rn(__fsub_rn(bj[t].z, bj[t].x), __fsub_rn(bj[t].w, bj[t].y));
    }
  }
  uint32_t supp = 0, keptbits = 0;
  for (int i = 0; i < n; ++i) {
    int owner = i & 63, word = i >> 6;
    uint32_t so = (uint32_t)__shfl((int)supp, owner, 64);
    bool kept_i = !((so >> word) & 1u);
    if (l == owner && kept_i) keptbits |= 1u << word;
    if (kept_i) {
      float4 bi = ob[i];
      float a1 = __fmul_rn(__fsub_rn(bi.z, bi.x), __fsub_rn(bi.w, bi.y));
#pragma unroll
      for (int t = 0; t < 4; ++t) {
        int j = l + 64 * t;
        if (j > i && j < n && !((supp >> t) & 1u)) {
          float ltx = fmaxf(bi.x, bj[t].x), lty = fmaxf(bi.y, bj[t].y);
          float rbx = fminf(bi.z, bj[t].z), rby = fminf(bi.w, bj[t].w);
          float dx = fmaxf(__fsub_rn(rbx, ltx), 0.0f);
          float dy = fmaxf(__fsub_rn(rby, lty), 0.0f);
          float inter = __fmul_rn(dx, dy);
          float uni = __fsub_rn(__fadd_rn(a1, aj[t]), inter);
          if (inter > 0.0f && __fdiv_rn(inter, uni) > IOU_T) supp |= 1u << t;
        }
      }
    }
  }
#pragma unroll
  for (int t = 0; t < 4; ++t) {
    int j = l + 64 * t;
    if (j < n && ((keptbits >> t) & 1u)) {
      uint32_t r = rk[j];
      atomicOr(&keepmask[b * 64 + (r >> 5)], 1u << (r & 31));
    }
  }
}

// ---------------- K6: emit up to 300 rows + count ----------------
__global__ __launch_bounds__(64) void k_out(const uint32_t* __restrict__ keepmask,
                                            const float4* __restrict__ box4,
                                            const float* __restrict__ topk_score,
                                            const float* __restrict__ clsf,
                                            float* __restrict__ out,
                                            float* __restrict__ out_counts) {
  const int b = blockIdx.x;
  const int l = threadIdx.x;
  float* ob = out + (size_t)b * MAXDET * 6;
  for (int t = l; t < MAXDET * 6; t += 64) ob[t] = 0.0f;
  __syncthreads();
  uint32_t w = keepmask[b * 64 + l];
  int pc = __popc(w);
  int pre = pc;
  for (int off = 1; off < 64; off <<= 1) {
    int v = __shfl_up(pre, off, 64);
    if (l >= off) pre += v;
  }
  if (l == 63) out_counts[b] = (float)pre;  // total kept
  int r = pre - pc;  // exclusive prefix of kept counts
  for (int jj = 0; jj < 32; ++jj) {
    if ((w >> jj) & 1u) {
      if (r < MAXDET) {
        int k = l * 32 + jj;
        float4 bx = box4[(size_t)b * TOPK + k];
        float sc = topk_score[(size_t)b * TOPK + k];
        float cf = clsf[(size_t)b * TOPK + k];
        float* row = ob + (size_t)r * 6;
        row[0] = bx.x; row[1] = bx.y; row[2] = bx.z; row[3] = bx.w;
        row[4] = sc;   row[5] = cf;
      }
      ++r;
    }
  }
}

extern "C" void kernel_launch(void* const* d_in, const int* in_sizes, int n_in,
                              void* d_out, int out_size, void* d_ws, size_t ws_size,
                              hipStream_t stream) {
  const float* pred = (const float*)d_in[0];
  float* out = (float*)d_out;

  char* ws = (char*)d_ws;
  size_t off = 0;
  // --- zeroed-each-launch region (contiguous) ---
  uint32_t* hist1 = (uint32_t*)(ws + off); off += (size_t)B_ * NBINS * 4;        // 256 KB
  uint32_t* keepmask = (uint32_t*)(ws + off); off += (size_t)B_ * 64 * 4;        // 4 KB
  uint32_t* cnt   = (uint32_t*)(ws + off); off += (size_t)B_ * CNT_STRIDE * 4;   // 2 KB
  float* topk_score = (float*)(ws + off);  off += (size_t)B_ * TOPK * 4;         // 128 KB
  size_t zero_bytes = off;
  // --- rest ---
  uint32_t* b1v   = (uint32_t*)(ws + off); off += 64;
  uint32_t* keys = (uint32_t*)(ws + off); off += (size_t)B_ * N_ * 4;            // 1.6 MB
  uint32_t* cls = (uint32_t*)(ws + off);  off += (size_t)B_ * N_ * 4;            // 1.6 MB
  unsigned long long* cand = (unsigned long long*)(ws + off); off += (size_t)B_ * CAP * 8;  // 786 KB
  float4* box4 = (float4*)(ws + off);      off += (size_t)B_ * TOPK * 16;        // 512 KB
  float* clsf = (float*)(ws + off);        off += (size_t)B_ * TOPK * 4;         // 128 KB

  (void)in_sizes; (void)n_in; (void)out_size; (void)ws_size;

  int n16 = (int)(zero_bytes / 16);
  k_zero<<<(n16 + 255) / 256, 256, 0, stream>>>((uint4*)ws, n16);
  int grid_n = (B_ * N_ + 255) / 256;
  k_score<<<grid_n, 256, 0, stream>>>(pred, keys, cls, hist1);
  k_thresh<<<B_, 256, 0, stream>>>(hist1, b1v);
  dim3 cgrid((N_ + 255) / 256, B_);
  k_compact<<<cgrid, 256, 0, stream>>>(keys, b1v, cnt, cand);
  dim3 rgrid(CAP / RANK_T, B_);
  k_rank<<<rgrid, RANK_T, 0, stream>>>(pred, cls, cand, cnt, topk_score, box4, clsf);
  dim3 ngrid(NC_, B_);
  k_nmscls<<<ngrid, 64, 0, stream>>>(box4, clsf, topk_score, keepmask);
  k_out<<<B_, 64, 0, stream>>>(keepmask, box4, topk_score, clsf, out,
                               out + (size_t)B_ * MAXDET * 6);
}